// Round 8
// baseline (245.181 us; speedup 1.0000x reference)
//
#include <hip/hip_runtime.h>
#include <hip/hip_bf16.h>

typedef __bf16 bf16_t;
typedef bf16_t bf16x4 __attribute__((ext_vector_type(4)));
typedef bf16_t bf16x8 __attribute__((ext_vector_type(8)));
typedef float f32x4 __attribute__((ext_vector_type(4)));

#define EMB 1024
#define HEADS 16
#define BATCH 2
#define SEQ 2048
#define HD 64
#define TOKENS (BATCH * SEQ)  // 4096

// async global->LDS, 16B per lane. LDS dest = wave-uniform base + lane*16.
__device__ __forceinline__ void gld16(bf16_t* lds_dst, const bf16_t* g_src) {
    __builtin_amdgcn_global_load_lds(
        (const __attribute__((address_space(1))) unsigned int*)g_src,
        (__attribute__((address_space(3))) unsigned int*)lds_dst, 16, 0, 0);
}

// ---------------------------------------------------------------------------
// x fp32 -> bf16 (elementwise). 1024 blocks x 256 thr x 16 elems = 4M.
// ---------------------------------------------------------------------------
__global__ __launch_bounds__(256) void convert_x(const float* __restrict__ x,
                                                 bf16_t* __restrict__ xb) {
    size_t i = ((size_t)blockIdx.x * 256 + threadIdx.x) * 16;
    f32x4 v0 = *(const f32x4*)&x[i];
    f32x4 v1 = *(const f32x4*)&x[i + 4];
    f32x4 v2 = *(const f32x4*)&x[i + 8];
    f32x4 v3 = *(const f32x4*)&x[i + 12];
    bf16x8 o0, o1;
#pragma unroll
    for (int j = 0; j < 4; ++j) {
        o0[j] = (bf16_t)v0[j]; o0[4 + j] = (bf16_t)v1[j];
        o1[j] = (bf16_t)v2[j]; o1[4 + j] = (bf16_t)v3[j];
    }
    *(bf16x8*)&xb[i] = o0;
    *(bf16x8*)&xb[i + 8] = o1;
}

// ---------------------------------------------------------------------------
// W[k][n] fp32 -> Wt[n][k] bf16, 64x64 tiles. grid (16,16,4), z picks matrix.
// ---------------------------------------------------------------------------
__global__ __launch_bounds__(256) void prep_w(
    const float* __restrict__ W0, const float* __restrict__ W1,
    const float* __restrict__ W2, const float* __restrict__ W3,
    bf16_t* __restrict__ T0, bf16_t* __restrict__ T1,
    bf16_t* __restrict__ T2, bf16_t* __restrict__ T3) {
    __shared__ __align__(16) bf16_t T[64][72];
    int z = blockIdx.z;
    const float* src = (z == 0) ? W0 : (z == 1) ? W1 : (z == 2) ? W2 : W3;
    bf16_t* dst = (z == 0) ? T0 : (z == 1) ? T1 : (z == 2) ? T2 : T3;
    int k0 = blockIdx.y * 64, n0 = blockIdx.x * 64;
    int r = threadIdx.x >> 2, c4 = (threadIdx.x & 3) * 16;
    f32x4 v[4];
#pragma unroll
    for (int q = 0; q < 4; ++q)
        v[q] = *(const f32x4*)&src[(size_t)(k0 + r) * 1024 + n0 + c4 + q * 4];
#pragma unroll
    for (int j = 0; j < 16; ++j) T[c4 + j][r] = (bf16_t)v[j >> 2][j & 3];
    __syncthreads();
    bf16x8 o0 = *(const bf16x8*)&T[r][c4];
    bf16x8 o1 = *(const bf16x8*)&T[r][c4 + 8];
    *(bf16x8*)&dst[(size_t)(n0 + r) * 1024 + k0 + c4] = o0;
    *(bf16x8*)&dst[(size_t)(n0 + r) * 1024 + k0 + c4 + 8] = o1;
}

// ---------------------------------------------------------------------------
// FUSED QKV GEMM: one block computes the (64m x 128n) tile of Q, K, AND V.
// A-tile staged ONCE per K-step (3x less A traffic), 24 MFMA per wave per
// barrier pair (3x amortization vs gemm64). BM=64 BN=128 BK=32, grid (8,64).
// Q -> (b,h,n,d) with QSCALE folded; K -> (b,h,n,d); V -> (b,h,d,n).
// ---------------------------------------------------------------------------
__global__ __launch_bounds__(256) void qkv_gemm(
    const bf16_t* __restrict__ A,
    const bf16_t* __restrict__ Wt0, const bf16_t* __restrict__ Wt1, const bf16_t* __restrict__ Wt2,
    const float* __restrict__ bq, const float* __restrict__ bk, const float* __restrict__ bv,
    bf16_t* __restrict__ Qb, bf16_t* __restrict__ Kb, bf16_t* __restrict__ Vtb,
    float qscale) {
    __shared__ __align__(16) bf16_t As[64 * 32];       // 4 KB
    __shared__ __align__(16) bf16_t Bs[3][128 * 32];   // 24 KB

    const int tid = threadIdx.x, w = tid >> 6, lane = tid & 63;
    const int quad = lane >> 4, c = lane & 15;
    const int wm = (w >> 1) * 32, wn = (w & 1) * 64;
    const int m0 = blockIdx.y * 64, n0 = blockIdx.x * 128;

    f32x4 acc[3][2][4];
#pragma unroll
    for (int i = 0; i < 3; ++i)
#pragma unroll
        for (int mt = 0; mt < 2; ++mt)
#pragma unroll
            for (int nt = 0; nt < 4; ++nt) acc[i][mt][nt] = (f32x4){0.f, 0.f, 0.f, 0.f};

    const int srow = lane >> 2, sch = lane & 3;  // 16 rows x 4 chunks / gld16
    const bf16_t* Ag = A + (size_t)m0 * 1024;
    const bf16_t* Bg[3] = {Wt0 + (size_t)n0 * 1024, Wt1 + (size_t)n0 * 1024,
                           Wt2 + (size_t)n0 * 1024};

    for (int k0 = 0; k0 < 1024; k0 += 32) {
        __syncthreads();
        gld16(&As[(w * 16) * 32], &Ag[(size_t)(w * 16 + srow) * 1024 + k0 + sch * 8]);
#pragma unroll
        for (int i = 0; i < 3; ++i)
#pragma unroll
            for (int s = 0; s < 2; ++s) {
                int rg = w * 32 + s * 16;
                gld16(&Bs[i][rg * 32], &Bg[i][(size_t)(rg + srow) * 1024 + k0 + sch * 8]);
            }
        __syncthreads();

        bf16x8 af[2];
#pragma unroll
        for (int t = 0; t < 2; ++t)
            af[t] = *(const bf16x8*)&As[(wm + t * 16 + c) * 32 + quad * 8];
#pragma unroll
        for (int i = 0; i < 3; ++i) {
#pragma unroll
            for (int nt = 0; nt < 4; ++nt) {
                bf16x8 bfv = *(const bf16x8*)&Bs[i][(wn + nt * 16 + c) * 32 + quad * 8];
#pragma unroll
                for (int mt = 0; mt < 2; ++mt)
                    acc[i][mt][nt] = __builtin_amdgcn_mfma_f32_16x16x32_bf16(
                        af[mt], bfv, acc[i][mt][nt], 0, 0, 0);
            }
        }
    }

    // Epilogue: Q (mode1, qscale), K (mode1), V (mode2)
#pragma unroll
    for (int i = 0; i < 3; ++i) {
        const float* bias = (i == 0) ? bq : (i == 1) ? bk : bv;
        const float scale = (i == 0) ? qscale : 1.0f;
#pragma unroll
        for (int nt = 0; nt < 4; ++nt) {
            int col = n0 + wn + nt * 16 + c;
            float bvv = bias[col];
            int hh = col >> 6, d = col & 63;
#pragma unroll
            for (int mt = 0; mt < 2; ++mt)
#pragma unroll
                for (int r = 0; r < 4; ++r) {
                    int row = m0 + wm + mt * 16 + quad * 4 + r;
                    int bb = row >> 11, n = row & 2047;
                    float v = (acc[i][mt][nt][r] + bvv) * scale;
                    if (i == 2) {
                        Vtb[((size_t)(bb * HEADS + hh) * HD + d) * SEQ + n] = (bf16_t)v;
                    } else {
                        bf16_t* dst = (i == 0) ? Qb : Kb;
                        dst[((size_t)(bb * HEADS + hh) * SEQ + n) * HD + d] = (bf16_t)v;
                    }
                }
        }
    }
}

// ---------------------------------------------------------------------------
// O-proj GEMM with register-pipelined staging: next K-tile prefetched into
// VGPRs during compute; ds_write commit at loop head. BM=64 BN=128 BK=32.
// out fp32 [row][col] + bias.
// ---------------------------------------------------------------------------
__global__ __launch_bounds__(256) void oproj_gemm(
    const bf16_t* __restrict__ A, const bf16_t* __restrict__ Wt,
    const float* __restrict__ bias, float* __restrict__ out) {
    __shared__ __align__(16) bf16_t As[64 * 32];   // 4 KB
    __shared__ __align__(16) bf16_t Bs[128 * 32];  // 8 KB

    const int tid = threadIdx.x, w = tid >> 6, lane = tid & 63;
    const int quad = lane >> 4, c = lane & 15;
    const int wm = (w >> 1) * 32, wn = (w & 1) * 64;
    const int m0 = blockIdx.y * 64, n0 = blockIdx.x * 128;

    f32x4 acc[2][4];
#pragma unroll
    for (int i = 0; i < 2; ++i)
#pragma unroll
        for (int j = 0; j < 4; ++j) acc[i][j] = (f32x4){0.f, 0.f, 0.f, 0.f};

    const int srow = lane >> 2, sch = lane & 3;
    const bf16_t* Ag = A + (size_t)m0 * 1024;
    const bf16_t* Bg = Wt + (size_t)n0 * 1024;

    bf16x8 abuf, bbuf[2];
    auto load_tile = [&](int k0) {
        abuf = *(const bf16x8*)&Ag[(size_t)(w * 16 + srow) * 1024 + k0 + sch * 8];
#pragma unroll
        for (int s = 0; s < 2; ++s)
            bbuf[s] = *(const bf16x8*)&Bg[(size_t)(w * 32 + s * 16 + srow) * 1024 + k0 + sch * 8];
    };
    load_tile(0);

    for (int k0 = 0; k0 < 1024; k0 += 32) {
        __syncthreads();  // prior frag reads done
        *(bf16x8*)&As[(w * 16 + srow) * 32 + sch * 8] = abuf;
#pragma unroll
        for (int s = 0; s < 2; ++s)
            *(bf16x8*)&Bs[(w * 32 + s * 16 + srow) * 32 + sch * 8] = bbuf[s];
        __syncthreads();  // tile visible
        if (k0 + 32 < 1024) load_tile(k0 + 32);  // prefetch overlaps compute

        bf16x8 af[2], bfv[4];
#pragma unroll
        for (int t = 0; t < 2; ++t)
            af[t] = *(const bf16x8*)&As[(wm + t * 16 + c) * 32 + quad * 8];
#pragma unroll
        for (int t = 0; t < 4; ++t)
            bfv[t] = *(const bf16x8*)&Bs[(wn + t * 16 + c) * 32 + quad * 8];
#pragma unroll
        for (int mt = 0; mt < 2; ++mt)
#pragma unroll
            for (int nt = 0; nt < 4; ++nt)
                acc[mt][nt] = __builtin_amdgcn_mfma_f32_16x16x32_bf16(
                    af[mt], bfv[nt], acc[mt][nt], 0, 0, 0);
    }

#pragma unroll
    for (int nt = 0; nt < 4; ++nt) {
        int col = n0 + wn + nt * 16 + c;
        float bv = bias[col];
#pragma unroll
        for (int mt = 0; mt < 2; ++mt)
#pragma unroll
            for (int r = 0; r < 4; ++r) {
                int row = m0 + wm + mt * 16 + quad * 4 + r;
                out[(size_t)row * 1024 + col] = acc[mt][nt][r] + bv;
            }
    }
}

// ---------------------------------------------------------------------------
// Flash attention with register-pipelined K/V staging (unchanged from R7).
// ---------------------------------------------------------------------------
__global__ __launch_bounds__(256) void attn_kernel(
    const bf16_t* __restrict__ Q, const bf16_t* __restrict__ K,
    const bf16_t* __restrict__ Vt, bf16_t* __restrict__ O) {
    __shared__ __align__(16) bf16_t Ks[128 * 64];      // [key][d]
    __shared__ __align__(16) bf16_t Vs[64 * 128];      // [d][key]
    __shared__ __align__(16) bf16_t Ps[4][2][16][72];  // per-wave P [q][key]
    __shared__ float Lbuf[2][2][64];

    const int tid = threadIdx.x, w = tid >> 6, lane = tid & 63;
    const int quad = lane >> 4, c = lane & 15;
    const int qh = w & 1, kh = w >> 1;
    const int bh = blockIdx.x, b = bh >> 4, h = bh & 15;
    const int q0 = blockIdx.y * 64;

    const bf16_t* Qg = Q + ((size_t)bh * SEQ + q0) * HD;
    bf16x8 qf[2][2];
#pragma unroll
    for (int u = 0; u < 2; ++u)
#pragma unroll
        for (int ks = 0; ks < 2; ++ks)
            qf[u][ks] = *(const bf16x8*)&Qg[(qh * 32 + u * 16 + c) * 64 + ks * 32 + quad * 8];

    f32x4 Oacc[2][4];
#pragma unroll
    for (int u = 0; u < 2; ++u)
#pragma unroll
        for (int t = 0; t < 4; ++t) Oacc[u][t] = (f32x4){0.f, 0.f, 0.f, 0.f};
    float lp[2] = {0.f, 0.f};

    const int kr = lane >> 3, kch = lane & 7;
    const int vr = lane >> 4, vch = lane & 15;

    const bf16_t* Kg = K + (size_t)bh * SEQ * HD;
    const bf16_t* Vg = Vt + (size_t)bh * HD * SEQ;

    bf16x8 kbuf[4], vbuf[4];
    auto load_tile = [&](int j0) {
#pragma unroll
        for (int s = 0; s < 4; ++s) {
            int krow = w * 32 + s * 8 + kr;
            kbuf[s] = *(const bf16x8*)&Kg[(size_t)(j0 + krow) * 64 + (kch ^ kr) * 8];
            int vrow = w * 16 + s * 4 + vr;
            vbuf[s] = *(const bf16x8*)&Vg[(size_t)vrow * SEQ + j0 + (vch ^ (vrow & 15)) * 8];
        }
    };
    load_tile(0);

    for (int j0 = 0; j0 < SEQ; j0 += 128) {
        __syncthreads();
#pragma unroll
        for (int s = 0; s < 4; ++s) {
            int krow = w * 32 + s * 8 + kr;
            *(bf16x8*)&Ks[krow * 64 + kch * 8] = kbuf[s];
            int vrow = w * 16 + s * 4 + vr;
            *(bf16x8*)&Vs[vrow * 128 + vch * 8] = vbuf[s];
        }
        __syncthreads();
        if (j0 + 128 < SEQ) load_tile(j0 + 128);

        f32x4 S[2][4];
#pragma unroll
        for (int u = 0; u < 2; ++u)
#pragma unroll
            for (int t = 0; t < 4; ++t) S[u][t] = (f32x4){0.f, 0.f, 0.f, 0.f};
#pragma unroll
        for (int ks = 0; ks < 2; ++ks)
#pragma unroll
            for (int t = 0; t < 4; ++t) {
                int row = kh * 64 + t * 16 + c;
                bf16x8 kv = *(const bf16x8*)&Ks[row * 64 + (((ks * 4 + quad) ^ (c & 7)) * 8)];
                S[0][t] = __builtin_amdgcn_mfma_f32_16x16x32_bf16(kv, qf[0][ks], S[0][t], 0, 0, 0);
                S[1][t] = __builtin_amdgcn_mfma_f32_16x16x32_bf16(kv, qf[1][ks], S[1][t], 0, 0, 0);
            }

#pragma unroll
        for (int u = 0; u < 2; ++u)
#pragma unroll
            for (int t = 0; t < 4; ++t) {
                bf16x4 pk;
#pragma unroll
                for (int r = 0; r < 4; ++r) {
                    float p = __builtin_amdgcn_exp2f(S[u][t][r]);
                    lp[u] += p;
                    pk[r] = (bf16_t)p;
                }
                *(bf16x4*)&Ps[w][u][c][t * 16 + quad * 4] = pk;
            }

#pragma unroll
        for (int ks2 = 0; ks2 < 2; ++ks2) {
            bf16x8 af0 = *(const bf16x8*)&Ps[w][0][c][ks2 * 32 + quad * 8];
            bf16x8 af1 = *(const bf16x8*)&Ps[w][1][c][ks2 * 32 + quad * 8];
#pragma unroll
            for (int t = 0; t < 4; ++t) {
                int row = t * 16 + c;
                bf16x8 vv = *(const bf16x8*)&Vs[row * 128 + (((kh * 8 + ks2 * 4 + quad) ^ c) * 8)];
                Oacc[0][t] = __builtin_amdgcn_mfma_f32_16x16x32_bf16(af0, vv, Oacc[0][t], 0, 0, 0);
                Oacc[1][t] = __builtin_amdgcn_mfma_f32_16x16x32_bf16(af1, vv, Oacc[1][t], 0, 0, 0);
            }
        }
    }

#pragma unroll
    for (int u = 0; u < 2; ++u) {
        lp[u] += __shfl_xor(lp[u], 16);
        lp[u] += __shfl_xor(lp[u], 32);
    }

    __syncthreads();
    float* Obuf = (float*)Ks;
    if (kh == 1) {
#pragma unroll
        for (int u = 0; u < 2; ++u) {
#pragma unroll
            for (int t = 0; t < 4; ++t)
                *(f32x4*)&Obuf[(((qh * 2 + u) * 4 + t) * 64 + lane) * 4] = Oacc[u][t];
            Lbuf[qh][u][lane] = lp[u];
        }
    }
    __syncthreads();
    if (kh == 0) {
        float lr[2][4];
#pragma unroll
        for (int u = 0; u < 2; ++u) {
            lp[u] += Lbuf[qh][u][lane];
#pragma unroll
            for (int r = 0; r < 4; ++r) lr[u][r] = __shfl(lp[u], quad * 4 + r);
        }
#pragma unroll
        for (int u = 0; u < 2; ++u)
#pragma unroll
            for (int t = 0; t < 4; ++t) {
                f32x4 part = *(const f32x4*)&Obuf[(((qh * 2 + u) * 4 + t) * 64 + lane) * 4];
#pragma unroll
                for (int r = 0; r < 4; ++r) {
                    int qrow = q0 + qh * 32 + u * 16 + quad * 4 + r;
                    size_t idx = ((size_t)(b * SEQ + qrow)) * EMB + h * 64 + t * 16 + c;
                    O[idx] = (bf16_t)((Oacc[u][t][r] + part[r]) / lr[u][r]);
                }
            }
    }
}

// ---------------------------------------------------------------------------
extern "C" void kernel_launch(void* const* d_in, const int* in_sizes, int n_in,
                              void* d_out, int out_size, void* d_ws, size_t ws_size,
                              hipStream_t stream) {
    (void)in_sizes; (void)n_in; (void)out_size; (void)ws_size;
    const float* x  = (const float*)d_in[0];
    const float* Wq = (const float*)d_in[1];
    const float* bq = (const float*)d_in[2];
    const float* Wk = (const float*)d_in[3];
    const float* bk = (const float*)d_in[4];
    const float* Wv = (const float*)d_in[5];
    const float* bv = (const float*)d_in[6];
    const float* Wo = (const float*)d_in[7];
    const float* bo = (const float*)d_in[8];

    bf16_t* ws = (bf16_t*)d_ws;
    const size_t NELEM = (size_t)TOKENS * EMB;  // 4M
    const size_t WELEM = (size_t)EMB * EMB;     // 1M
    bf16_t* Qb  = ws;
    bf16_t* Kb  = ws + NELEM;
    bf16_t* Vtb = ws + 2 * NELEM;   // V in (b,h,d,n)
    bf16_t* Ob  = ws + 3 * NELEM;
    bf16_t* xb  = ws + 4 * NELEM;
    bf16_t* Wt0 = ws + 5 * NELEM;
    bf16_t* Wt1 = Wt0 + WELEM;
    bf16_t* Wt2 = Wt0 + 2 * WELEM;
    bf16_t* Wt3 = Wt0 + 3 * WELEM;  // 48 MB total

    const float QSCALE = 1.4426950408889634f / 32.0f;  // log2(e)/sqrt(EMB)

    hipLaunchKernelGGL(convert_x, dim3(1024), dim3(256), 0, stream, x, xb);
    hipLaunchKernelGGL(prep_w, dim3(16, 16, 4), dim3(256), 0, stream,
                       Wq, Wk, Wv, Wo, Wt0, Wt1, Wt2, Wt3);
    hipLaunchKernelGGL(qkv_gemm, dim3(8, 64), dim3(256), 0, stream,
                       xb, Wt0, Wt1, Wt2, bq, bk, bv, Qb, Kb, Vtb, QSCALE);
    hipLaunchKernelGGL(attn_kernel, dim3(32, 32), dim3(256), 0, stream, Qb, Kb, Vtb, Ob);
    hipLaunchKernelGGL(oproj_gemm, dim3(8, 64), dim3(256), 0, stream,
                       Ob, Wt3, bo, (float*)d_out);
}

// Round 9
// 229.872 us; speedup vs baseline: 1.0666x; 1.0666x over previous
//
#include <hip/hip_runtime.h>
#include <hip/hip_bf16.h>

typedef __bf16 bf16_t;
typedef bf16_t bf16x4 __attribute__((ext_vector_type(4)));
typedef bf16_t bf16x8 __attribute__((ext_vector_type(8)));
typedef float f32x4 __attribute__((ext_vector_type(4)));

#define EMB 1024
#define HEADS 16
#define BATCH 2
#define SEQ 2048
#define HD 64
#define TOKENS (BATCH * SEQ)  // 4096

// async global->LDS, 16B per lane. LDS dest = wave-uniform base + lane*16.
__device__ __forceinline__ void gld16(bf16_t* lds_dst, const bf16_t* g_src) {
    __builtin_amdgcn_global_load_lds(
        (const __attribute__((address_space(1))) unsigned int*)g_src,
        (__attribute__((address_space(3))) unsigned int*)lds_dst, 16, 0, 0);
}

// ---------------------------------------------------------------------------
// Combined prep: z<4 -> W_z[k][n] fp32 -> Wt[n][k] bf16 (64x64 tiles);
// z>=4 -> x fp32 -> bf16, 4096-elem chunks. grid (16,16,8) x 256 thr.
// ---------------------------------------------------------------------------
__global__ __launch_bounds__(256) void prep_all(
    const float* __restrict__ x, bf16_t* __restrict__ xb,
    const float* __restrict__ W0, const float* __restrict__ W1,
    const float* __restrict__ W2, const float* __restrict__ W3,
    bf16_t* __restrict__ T0, bf16_t* __restrict__ T1,
    bf16_t* __restrict__ T2, bf16_t* __restrict__ T3) {
    __shared__ __align__(16) bf16_t T[64][72];
    const int z = blockIdx.z;
    if (z < 4) {
        const float* src = (z == 0) ? W0 : (z == 1) ? W1 : (z == 2) ? W2 : W3;
        bf16_t* dst = (z == 0) ? T0 : (z == 1) ? T1 : (z == 2) ? T2 : T3;
        int k0 = blockIdx.y * 64, n0 = blockIdx.x * 64;
        int r = threadIdx.x >> 2, c4 = (threadIdx.x & 3) * 16;
        f32x4 v[4];
#pragma unroll
        for (int q = 0; q < 4; ++q)
            v[q] = *(const f32x4*)&src[(size_t)(k0 + r) * 1024 + n0 + c4 + q * 4];
#pragma unroll
        for (int j = 0; j < 16; ++j) T[c4 + j][r] = (bf16_t)v[j >> 2][j & 3];
        __syncthreads();
        bf16x8 o0 = *(const bf16x8*)&T[r][c4];
        bf16x8 o1 = *(const bf16x8*)&T[r][c4 + 8];
        *(bf16x8*)&dst[(size_t)(n0 + r) * 1024 + k0 + c4] = o0;
        *(bf16x8*)&dst[(size_t)(n0 + r) * 1024 + k0 + c4 + 8] = o1;
    } else {
        int blk = (z - 4) * 256 + blockIdx.y * 16 + blockIdx.x;  // 0..1023
        size_t i = ((size_t)blk * 256 + threadIdx.x) * 16;
        f32x4 v0 = *(const f32x4*)&x[i];
        f32x4 v1 = *(const f32x4*)&x[i + 4];
        f32x4 v2 = *(const f32x4*)&x[i + 8];
        f32x4 v3 = *(const f32x4*)&x[i + 12];
        bf16x8 o0, o1;
#pragma unroll
        for (int j = 0; j < 4; ++j) {
            o0[j] = (bf16_t)v0[j]; o0[4 + j] = (bf16_t)v1[j];
            o1[j] = (bf16_t)v2[j]; o1[4 + j] = (bf16_t)v3[j];
        }
        *(bf16x8*)&xb[i] = o0;
        *(bf16x8*)&xb[i + 8] = o1;
    }
}

// ---------------------------------------------------------------------------
// BARRIER-FREE QKV GEMM. Each WAVE owns a 64m x 64n tile and stages its own
// A/B tiles into its private 8 KB LDS slice via global_load_lds; the only
// waits are per-wave s_waitcnt(0) -> wave stalls are independent, hidden by
// TLP (no __syncthreads convoy). grid (16 n, 16 m, 3 z), 768 blocks.
// z=0: Q->(b,h,n,d) *qscale; z=1: K->(b,h,n,d); z=2: V->(b,h,d,n).
// ---------------------------------------------------------------------------
__global__ __launch_bounds__(256) void qkv_gemm(
    const bf16_t* __restrict__ A,
    const bf16_t* __restrict__ Wt0, const bf16_t* __restrict__ Wt1, const bf16_t* __restrict__ Wt2,
    const float* __restrict__ bq, const float* __restrict__ bk, const float* __restrict__ bv,
    bf16_t* __restrict__ Qb, bf16_t* __restrict__ Kb, bf16_t* __restrict__ Vtb,
    float qscale) {
    __shared__ __align__(16) bf16_t lds[4 * 4096];  // 8 KB per wave

    const int tid = threadIdx.x, w = tid >> 6, lane = tid & 63;
    const int quad = lane >> 4, c = lane & 15;
    bf16_t* Aw = &lds[w * 4096];   // [64 rows][32 k]
    bf16_t* Bw = Aw + 2048;        // [64 rows][32 k]

    const int z = blockIdx.z;
    const bf16_t* Wt = (z == 0) ? Wt0 : (z == 1) ? Wt1 : Wt2;
    const int m0 = blockIdx.y * 256 + w * 64, n0 = blockIdx.x * 64;
    const int srow = lane >> 2, sch = lane & 3;  // 16 rows x 4 chunks per gld16

    const bf16_t* Ag = A + (size_t)m0 * 1024;
    const bf16_t* Bg = Wt + (size_t)n0 * 1024;

    f32x4 acc[4][4];
#pragma unroll
    for (int i = 0; i < 4; ++i)
#pragma unroll
        for (int j = 0; j < 4; ++j) acc[i][j] = (f32x4){0.f, 0.f, 0.f, 0.f};

    for (int k0 = 0; k0 < 1024; k0 += 32) {
        // wave-private: prior iter's ds_reads fully retired before overwrite
        __builtin_amdgcn_s_waitcnt(0);
#pragma unroll
        for (int s = 0; s < 4; ++s) {
            gld16(&Aw[s * 512], &Ag[(size_t)(s * 16 + srow) * 1024 + k0 + sch * 8]);
            gld16(&Bw[s * 512], &Bg[(size_t)(s * 16 + srow) * 1024 + k0 + sch * 8]);
        }
        __builtin_amdgcn_s_waitcnt(0);  // staging landed (this wave only)

        bf16x8 af[4], bfv[4];
#pragma unroll
        for (int t = 0; t < 4; ++t)
            af[t] = *(const bf16x8*)&Aw[(t * 16 + c) * 32 + quad * 8];
#pragma unroll
        for (int t = 0; t < 4; ++t)
            bfv[t] = *(const bf16x8*)&Bw[(t * 16 + c) * 32 + quad * 8];
#pragma unroll
        for (int mt = 0; mt < 4; ++mt)
#pragma unroll
            for (int nt = 0; nt < 4; ++nt)
                acc[mt][nt] = __builtin_amdgcn_mfma_f32_16x16x32_bf16(
                    af[mt], bfv[nt], acc[mt][nt], 0, 0, 0);
    }

    const float* bias = (z == 0) ? bq : (z == 1) ? bk : bv;
    const float scale = (z == 0) ? qscale : 1.0f;
#pragma unroll
    for (int nt = 0; nt < 4; ++nt) {
        int col = n0 + nt * 16 + c;
        float bvv = bias[col];
        int hh = col >> 6, d = col & 63;
#pragma unroll
        for (int mt = 0; mt < 4; ++mt)
#pragma unroll
            for (int r = 0; r < 4; ++r) {
                int row = m0 + mt * 16 + quad * 4 + r;
                int bb = row >> 11, n = row & 2047;
                float v = (acc[mt][nt][r] + bvv) * scale;
                if (z == 2)
                    Vtb[((size_t)(bb * HEADS + hh) * HD + d) * SEQ + n] = (bf16_t)v;
                else if (z == 0)
                    Qb[((size_t)(bb * HEADS + hh) * SEQ + n) * HD + d] = (bf16_t)v;
                else
                    Kb[((size_t)(bb * HEADS + hh) * SEQ + n) * HD + d] = (bf16_t)v;
            }
    }
}

// ---------------------------------------------------------------------------
// BARRIER-FREE O-proj GEMM: wave tile 32m x 32n, private 4 KB LDS slice.
// grid (32 n, 32 m) = 1024 blocks (~4/CU, 16 waves/CU). fp32 out + bias.
// ---------------------------------------------------------------------------
__global__ __launch_bounds__(256) void oproj_gemm(
    const bf16_t* __restrict__ A, const bf16_t* __restrict__ Wt,
    const float* __restrict__ bias, float* __restrict__ out) {
    __shared__ __align__(16) bf16_t lds[4 * 2048];  // 4 KB per wave

    const int tid = threadIdx.x, w = tid >> 6, lane = tid & 63;
    const int quad = lane >> 4, c = lane & 15;
    bf16_t* Aw = &lds[w * 2048];   // [32 rows][32 k]
    bf16_t* Bw = Aw + 1024;        // [32 rows][32 k]

    const int m0 = blockIdx.y * 128 + w * 32, n0 = blockIdx.x * 32;
    const int srow = lane >> 2, sch = lane & 3;

    const bf16_t* Ag = A + (size_t)m0 * 1024;
    const bf16_t* Bg = Wt + (size_t)n0 * 1024;

    f32x4 acc[2][2];
#pragma unroll
    for (int i = 0; i < 2; ++i)
#pragma unroll
        for (int j = 0; j < 2; ++j) acc[i][j] = (f32x4){0.f, 0.f, 0.f, 0.f};

    for (int k0 = 0; k0 < 1024; k0 += 32) {
        __builtin_amdgcn_s_waitcnt(0);
#pragma unroll
        for (int s = 0; s < 2; ++s) {
            gld16(&Aw[s * 512], &Ag[(size_t)(s * 16 + srow) * 1024 + k0 + sch * 8]);
            gld16(&Bw[s * 512], &Bg[(size_t)(s * 16 + srow) * 1024 + k0 + sch * 8]);
        }
        __builtin_amdgcn_s_waitcnt(0);

        bf16x8 af[2], bfv[2];
#pragma unroll
        for (int t = 0; t < 2; ++t)
            af[t] = *(const bf16x8*)&Aw[(t * 16 + c) * 32 + quad * 8];
#pragma unroll
        for (int t = 0; t < 2; ++t)
            bfv[t] = *(const bf16x8*)&Bw[(t * 16 + c) * 32 + quad * 8];
#pragma unroll
        for (int mt = 0; mt < 2; ++mt)
#pragma unroll
            for (int nt = 0; nt < 2; ++nt)
                acc[mt][nt] = __builtin_amdgcn_mfma_f32_16x16x32_bf16(
                    af[mt], bfv[nt], acc[mt][nt], 0, 0, 0);
    }

#pragma unroll
    for (int nt = 0; nt < 2; ++nt) {
        int col = n0 + nt * 16 + c;
        float bv = bias[col];
#pragma unroll
        for (int mt = 0; mt < 2; ++mt)
#pragma unroll
            for (int r = 0; r < 4; ++r) {
                int row = m0 + mt * 16 + quad * 4 + r;
                out[(size_t)row * 1024 + col] = acc[mt][nt][r] + bv;
            }
    }
}

// ---------------------------------------------------------------------------
// Flash attention with register-pipelined K/V staging (unchanged from R7).
// ---------------------------------------------------------------------------
__global__ __launch_bounds__(256) void attn_kernel(
    const bf16_t* __restrict__ Q, const bf16_t* __restrict__ K,
    const bf16_t* __restrict__ Vt, bf16_t* __restrict__ O) {
    __shared__ __align__(16) bf16_t Ks[128 * 64];      // [key][d]
    __shared__ __align__(16) bf16_t Vs[64 * 128];      // [d][key]
    __shared__ __align__(16) bf16_t Ps[4][2][16][72];  // per-wave P [q][key]
    __shared__ float Lbuf[2][2][64];

    const int tid = threadIdx.x, w = tid >> 6, lane = tid & 63;
    const int quad = lane >> 4, c = lane & 15;
    const int qh = w & 1, kh = w >> 1;
    const int bh = blockIdx.x, b = bh >> 4, h = bh & 15;
    const int q0 = blockIdx.y * 64;

    const bf16_t* Qg = Q + ((size_t)bh * SEQ + q0) * HD;
    bf16x8 qf[2][2];
#pragma unroll
    for (int u = 0; u < 2; ++u)
#pragma unroll
        for (int ks = 0; ks < 2; ++ks)
            qf[u][ks] = *(const bf16x8*)&Qg[(qh * 32 + u * 16 + c) * 64 + ks * 32 + quad * 8];

    f32x4 Oacc[2][4];
#pragma unroll
    for (int u = 0; u < 2; ++u)
#pragma unroll
        for (int t = 0; t < 4; ++t) Oacc[u][t] = (f32x4){0.f, 0.f, 0.f, 0.f};
    float lp[2] = {0.f, 0.f};

    const int kr = lane >> 3, kch = lane & 7;
    const int vr = lane >> 4, vch = lane & 15;

    const bf16_t* Kg = K + (size_t)bh * SEQ * HD;
    const bf16_t* Vg = Vt + (size_t)bh * HD * SEQ;

    bf16x8 kbuf[4], vbuf[4];
    auto load_tile = [&](int j0) {
#pragma unroll
        for (int s = 0; s < 4; ++s) {
            int krow = w * 32 + s * 8 + kr;
            kbuf[s] = *(const bf16x8*)&Kg[(size_t)(j0 + krow) * 64 + (kch ^ kr) * 8];
            int vrow = w * 16 + s * 4 + vr;
            vbuf[s] = *(const bf16x8*)&Vg[(size_t)vrow * SEQ + j0 + (vch ^ (vrow & 15)) * 8];
        }
    };
    load_tile(0);

    for (int j0 = 0; j0 < SEQ; j0 += 128) {
        __syncthreads();
#pragma unroll
        for (int s = 0; s < 4; ++s) {
            int krow = w * 32 + s * 8 + kr;
            *(bf16x8*)&Ks[krow * 64 + kch * 8] = kbuf[s];
            int vrow = w * 16 + s * 4 + vr;
            *(bf16x8*)&Vs[vrow * 128 + vch * 8] = vbuf[s];
        }
        __syncthreads();
        if (j0 + 128 < SEQ) load_tile(j0 + 128);

        f32x4 S[2][4];
#pragma unroll
        for (int u = 0; u < 2; ++u)
#pragma unroll
            for (int t = 0; t < 4; ++t) S[u][t] = (f32x4){0.f, 0.f, 0.f, 0.f};
#pragma unroll
        for (int ks = 0; ks < 2; ++ks)
#pragma unroll
            for (int t = 0; t < 4; ++t) {
                int row = kh * 64 + t * 16 + c;
                bf16x8 kv = *(const bf16x8*)&Ks[row * 64 + (((ks * 4 + quad) ^ (c & 7)) * 8)];
                S[0][t] = __builtin_amdgcn_mfma_f32_16x16x32_bf16(kv, qf[0][ks], S[0][t], 0, 0, 0);
                S[1][t] = __builtin_amdgcn_mfma_f32_16x16x32_bf16(kv, qf[1][ks], S[1][t], 0, 0, 0);
            }

#pragma unroll
        for (int u = 0; u < 2; ++u)
#pragma unroll
            for (int t = 0; t < 4; ++t) {
                bf16x4 pk;
#pragma unroll
                for (int r = 0; r < 4; ++r) {
                    float p = __builtin_amdgcn_exp2f(S[u][t][r]);
                    lp[u] += p;
                    pk[r] = (bf16_t)p;
                }
                *(bf16x4*)&Ps[w][u][c][t * 16 + quad * 4] = pk;
            }

#pragma unroll
        for (int ks2 = 0; ks2 < 2; ++ks2) {
            bf16x8 af0 = *(const bf16x8*)&Ps[w][0][c][ks2 * 32 + quad * 8];
            bf16x8 af1 = *(const bf16x8*)&Ps[w][1][c][ks2 * 32 + quad * 8];
#pragma unroll
            for (int t = 0; t < 4; ++t) {
                int row = t * 16 + c;
                bf16x8 vv = *(const bf16x8*)&Vs[row * 128 + (((kh * 8 + ks2 * 4 + quad) ^ c) * 8)];
                Oacc[0][t] = __builtin_amdgcn_mfma_f32_16x16x32_bf16(af0, vv, Oacc[0][t], 0, 0, 0);
                Oacc[1][t] = __builtin_amdgcn_mfma_f32_16x16x32_bf16(af1, vv, Oacc[1][t], 0, 0, 0);
            }
        }
    }

#pragma unroll
    for (int u = 0; u < 2; ++u) {
        lp[u] += __shfl_xor(lp[u], 16);
        lp[u] += __shfl_xor(lp[u], 32);
    }

    __syncthreads();
    float* Obuf = (float*)Ks;
    if (kh == 1) {
#pragma unroll
        for (int u = 0; u < 2; ++u) {
#pragma unroll
            for (int t = 0; t < 4; ++t)
                *(f32x4*)&Obuf[(((qh * 2 + u) * 4 + t) * 64 + lane) * 4] = Oacc[u][t];
            Lbuf[qh][u][lane] = lp[u];
        }
    }
    __syncthreads();
    if (kh == 0) {
        float lr[2][4];
#pragma unroll
        for (int u = 0; u < 2; ++u) {
            lp[u] += Lbuf[qh][u][lane];
#pragma unroll
            for (int r = 0; r < 4; ++r) lr[u][r] = __shfl(lp[u], quad * 4 + r);
        }
#pragma unroll
        for (int u = 0; u < 2; ++u)
#pragma unroll
            for (int t = 0; t < 4; ++t) {
                f32x4 part = *(const f32x4*)&Obuf[(((qh * 2 + u) * 4 + t) * 64 + lane) * 4];
#pragma unroll
                for (int r = 0; r < 4; ++r) {
                    int qrow = q0 + qh * 32 + u * 16 + quad * 4 + r;
                    size_t idx = ((size_t)(b * SEQ + qrow)) * EMB + h * 64 + t * 16 + c;
                    O[idx] = (bf16_t)((Oacc[u][t][r] + part[r]) / lr[u][r]);
                }
            }
    }
}

// ---------------------------------------------------------------------------
extern "C" void kernel_launch(void* const* d_in, const int* in_sizes, int n_in,
                              void* d_out, int out_size, void* d_ws, size_t ws_size,
                              hipStream_t stream) {
    (void)in_sizes; (void)n_in; (void)out_size; (void)ws_size;
    const float* x  = (const float*)d_in[0];
    const float* Wq = (const float*)d_in[1];
    const float* bq = (const float*)d_in[2];
    const float* Wk = (const float*)d_in[3];
    const float* bk = (const float*)d_in[4];
    const float* Wv = (const float*)d_in[5];
    const float* bv = (const float*)d_in[6];
    const float* Wo = (const float*)d_in[7];
    const float* bo = (const float*)d_in[8];

    bf16_t* ws = (bf16_t*)d_ws;
    const size_t NELEM = (size_t)TOKENS * EMB;  // 4M
    const size_t WELEM = (size_t)EMB * EMB;     // 1M
    bf16_t* Qb  = ws;
    bf16_t* Kb  = ws + NELEM;
    bf16_t* Vtb = ws + 2 * NELEM;   // V in (b,h,d,n)
    bf16_t* Ob  = ws + 3 * NELEM;
    bf16_t* xb  = ws + 4 * NELEM;
    bf16_t* Wt0 = ws + 5 * NELEM;
    bf16_t* Wt1 = Wt0 + WELEM;
    bf16_t* Wt2 = Wt0 + 2 * WELEM;
    bf16_t* Wt3 = Wt0 + 3 * WELEM;  // 48 MB total

    const float QSCALE = 1.4426950408889634f / 32.0f;  // log2(e)/sqrt(EMB)

    hipLaunchKernelGGL(prep_all, dim3(16, 16, 8), dim3(256), 0, stream,
                       x, xb, Wq, Wk, Wv, Wo, Wt0, Wt1, Wt2, Wt3);
    hipLaunchKernelGGL(qkv_gemm, dim3(16, 16, 3), dim3(256), 0, stream,
                       xb, Wt0, Wt1, Wt2, bq, bk, bv, Qb, Kb, Vtb, QSCALE);
    hipLaunchKernelGGL(attn_kernel, dim3(32, 32), dim3(256), 0, stream, Qb, Kb, Vtb, Ob);
    hipLaunchKernelGGL(oproj_gemm, dim3(32, 32), dim3(256), 0, stream,
                       Ob, Wt3, bo, (float*)d_out);
}